// Round 4
// baseline (427.287 us; speedup 1.0000x reference)
//
#include <hip/hip_runtime.h>
#include <hip/hip_bf16.h>

#define NTOK 8192   // B*T
#define DM   1024
#define TT   2048
#define NH   16
#define BH_STRIDE (TT * 64)   // 131072 elems per (b,h) in permuted Q/K

typedef __hip_bfloat16 bf16;
typedef short bf16x8 __attribute__((ext_vector_type(8)));
typedef float f32x4  __attribute__((ext_vector_type(4)));
typedef float f32x16 __attribute__((ext_vector_type(16)));

#define N4_QK 2097152   // 8192*1024/4
#define N4_W  262144    // 1024*1024/4
#define N4_ONES 2048    // 8192/4

__device__ __forceinline__ void gload_lds16(const void* g, void* l) {
  __builtin_amdgcn_global_load_lds(
      (const __attribute__((address_space(1))) unsigned int*)g,
      (__attribute__((address_space(3))) unsigned int*)l, 16, 0, 0);
}

// ---- fused fp32->bf16 cvt (q,k,wq,wk -> contiguous bf16 ws) + ones for out0 ----
__global__ void prep_k(const float* __restrict__ q, const float* __restrict__ k,
                       const float* __restrict__ wq, const float* __restrict__ wk,
                       bf16* __restrict__ dst, float* __restrict__ ones) {
  const int i = blockIdx.x * 256 + threadIdx.x;
  const int total_cvt = 2 * N4_QK + 2 * N4_W;
  if (i < total_cvt) {
    const float* src;
    if (i < N4_QK)            src = q  + (size_t)i * 4;
    else if (i < 2 * N4_QK)   src = k  + (size_t)(i - N4_QK) * 4;
    else if (i < 2 * N4_QK + N4_W) src = wq + (size_t)(i - 2 * N4_QK) * 4;
    else                      src = wk + (size_t)(i - 2 * N4_QK - N4_W) * 4;
    float4 v = *reinterpret_cast<const float4*>(src);
    bf16 o[4] = {__float2bfloat16(v.x), __float2bfloat16(v.y),
                 __float2bfloat16(v.z), __float2bfloat16(v.w)};
    reinterpret_cast<ushort4*>(dst)[i] = *reinterpret_cast<ushort4*>(o);
  } else {
    const int j = i - total_cvt;          // 0..2047
    reinterpret_cast<float4*>(ones)[j] = make_float4(1.f, 1.f, 1.f, 1.f);
  }
}

// ---- merged projection GEMM, epilogue writes PERMUTED fragment-native layout ----
// Qp/Kp[(b*16+h)][tc(64)][t(4)][lh(2)][tk(32)][e(8)]: element (tok,d) at
// tc=tok>>5, tk=tok&31, t=d>>4, lh=(d>>3)&1, e=d&7.
__global__ void gemm_qk(const bf16* __restrict__ Aq, const bf16* __restrict__ Ak,
                        const bf16* __restrict__ W,
                        const float* __restrict__ bq, const float* __restrict__ bk,
                        bf16* __restrict__ Qp, bf16* __restrict__ Kp)
{
  __shared__ bf16 sA[128 * 64];
  __shared__ bf16 sB[128 * 64];
  const int tid  = threadIdx.x;
  const int lane = tid & 63;
  const int wave = tid >> 6;
  const int bm   = (blockIdx.x >> 4) << 7;
  const int bn   = (blockIdx.x & 15) << 7;
  const bool isQ = bn < 1024;
  const bf16* __restrict__ A = isQ ? Aq : Ak;
  const float scale = isQ ? 0.18033688011112042f : 1.0f;  // log2(e)/8
  const float* __restrict__ bias = isQ ? bq : (bk - 1024);
  bf16* __restrict__ dst = isQ ? Qp : Kp;

  const int wr   = (wave >> 1) << 6;
  const int wc   = (wave & 1) << 6;
  const int lrow = lane & 15;
  const int lk8  = (lane >> 4) << 3;
  const int trow = tid >> 3;
  const int tcol = (tid & 7) << 3;

  f32x4 acc[4][4] = {};

  for (int k0 = 0; k0 < 1024; k0 += 64) {
#pragma unroll
    for (int i = 0; i < 4; ++i) {
      const int r = trow + i * 32;
      gload_lds16(A + (size_t)(bm + r) * 1024 + k0 + tcol, sA + r * 64 + tcol);
      gload_lds16(W + (size_t)(bn + r) * 1024 + k0 + tcol, sB + r * 64 + tcol);
    }
    __syncthreads();

    bf16x8 af[4][2], bfr[4][2];
#pragma unroll
    for (int mi = 0; mi < 4; ++mi) {
      af[mi][0]  = *reinterpret_cast<const bf16x8*>(sA + (wr + mi * 16 + lrow) * 64 + lk8);
      af[mi][1]  = *reinterpret_cast<const bf16x8*>(sA + (wr + mi * 16 + lrow) * 64 + 32 + lk8);
      bfr[mi][0] = *reinterpret_cast<const bf16x8*>(sB + (wc + mi * 16 + lrow) * 64 + lk8);
      bfr[mi][1] = *reinterpret_cast<const bf16x8*>(sB + (wc + mi * 16 + lrow) * 64 + 32 + lk8);
    }
#pragma unroll
    for (int mi = 0; mi < 4; ++mi)
#pragma unroll
      for (int ni = 0; ni < 4; ++ni) {
        acc[mi][ni] = __builtin_amdgcn_mfma_f32_16x16x32_bf16(af[mi][0], bfr[ni][0], acc[mi][ni], 0, 0, 0);
        acc[mi][ni] = __builtin_amdgcn_mfma_f32_16x16x32_bf16(af[mi][1], bfr[ni][1], acc[mi][ni], 0, 0, 0);
      }
    __syncthreads();
  }

#pragma unroll
  for (int mi = 0; mi < 4; ++mi)
#pragma unroll
    for (int ni = 0; ni < 4; ++ni) {
      const int col = bn + wc + ni * 16 + lrow;          // global feature 0..2047
      const float bv = bias[col];
      const int d  = col & 63;
      const int hh = (col >> 6) & 15;
      const size_t doff = (size_t)((d >> 4) * 2 + ((d >> 3) & 1)) * 256 + (d & 7);
#pragma unroll
      for (int j = 0; j < 4; ++j) {
        const int row = bm + wr + mi * 16 + ((lane >> 4) << 2) + j;  // token 0..8191
        const int bb  = row >> 11;
        const int tok = row & (TT - 1);
        const size_t idx = (size_t)(bb * NH + hh) * BH_STRIDE
                         + (size_t)(tok >> 5) * 2048 + doff + (size_t)(tok & 31) * 8;
        dst[idx] = __float2bfloat16((acc[mi][ni][j] + bv) * scale);
      }
    }
}

// ---- fused QK^T + softmax, 2-tile pipelined: pass2(A) overlaps pass1(B) ----
// grid (8, 64): x = 256-row q-super-tile, y = b*16+h. Each wave owns two
// 32-row chunks (tcA, tcB = tcA+4). Plain (cached) stores, exp2-folded norm.
__global__ __launch_bounds__(256, 2) void attn3_k(
    const bf16* __restrict__ Qp, const bf16* __restrict__ Kp, float* __restrict__ attn)
{
  const int lane = threadIdx.x & 63;
  const int wave = threadIdx.x >> 6;
  const int l31  = lane & 31;
  const int lh   = lane >> 5;
  const int bh   = blockIdx.y;
  const int tcA  = blockIdx.x * 8 + wave;
  const int tcB  = tcA + 4;
  const int q0A  = blockIdx.x * 256 + wave * 32;
  const int q0B  = q0A + 128;

  const bf16* qbase = Qp + (size_t)bh * BH_STRIDE + lh * 256 + l31 * 8;
  bf16x8 aqA[4], aqB[4];
#pragma unroll
  for (int t = 0; t < 4; ++t) {
    aqA[t] = *reinterpret_cast<const bf16x8*>(qbase + (size_t)tcA * 2048 + t * 512);
    aqB[t] = *reinterpret_cast<const bf16x8*>(qbase + (size_t)tcB * 2048 + t * 512);
  }

  const bf16* kb = Kp + (size_t)bh * BH_STRIDE + lh * 256 + l31 * 8;

  float sA[16], sB[16];
#pragma unroll
  for (int r = 0; r < 16; ++r) { sA[r] = 0.f; sB[r] = 0.f; }

  // ---- pass 1 (tile A): row sums of exp2(S) ----
  for (int nc = 0; nc < 64; ++nc) {
    const bf16* kp = kb + (size_t)nc * 2048;
    bf16x8 bk0 = *reinterpret_cast<const bf16x8*>(kp);
    bf16x8 bk1 = *reinterpret_cast<const bf16x8*>(kp + 512);
    bf16x8 bk2 = *reinterpret_cast<const bf16x8*>(kp + 1024);
    bf16x8 bk3 = *reinterpret_cast<const bf16x8*>(kp + 1536);
    f32x16 acc = {};
    acc = __builtin_amdgcn_mfma_f32_32x32x16_bf16(aqA[0], bk0, acc, 0, 0, 0);
    acc = __builtin_amdgcn_mfma_f32_32x32x16_bf16(aqA[1], bk1, acc, 0, 0, 0);
    acc = __builtin_amdgcn_mfma_f32_32x32x16_bf16(aqA[2], bk2, acc, 0, 0, 0);
    acc = __builtin_amdgcn_mfma_f32_32x32x16_bf16(aqA[3], bk3, acc, 0, 0, 0);
#pragma unroll
    for (int r = 0; r < 16; ++r) sA[r] += __builtin_amdgcn_exp2f(acc[r]);
  }

#pragma unroll
  for (int r = 0; r < 16; ++r) {
    float sr = sA[r];
    sr += __shfl_xor(sr, 1);
    sr += __shfl_xor(sr, 2);
    sr += __shfl_xor(sr, 4);
    sr += __shfl_xor(sr, 8);
    sr += __shfl_xor(sr, 16);
    sA[r] = -__builtin_amdgcn_logf(sr);   // log2; p = exp2(acc + sA)
  }

  float* obA = attn + ((size_t)bh * TT + q0A + 4 * lh) * TT + l31;
  float* obB = attn + ((size_t)bh * TT + q0B + 4 * lh) * TT + l31;

  // ---- middle: pass 2 (A) stores + pass 1 (B) sums, shared K stream ----
  for (int nc = 0; nc < 64; ++nc) {
    const bf16* kp = kb + (size_t)nc * 2048;
    bf16x8 bk0 = *reinterpret_cast<const bf16x8*>(kp);
    bf16x8 bk1 = *reinterpret_cast<const bf16x8*>(kp + 512);
    bf16x8 bk2 = *reinterpret_cast<const bf16x8*>(kp + 1024);
    bf16x8 bk3 = *reinterpret_cast<const bf16x8*>(kp + 1536);
    f32x16 accA = {}, accB = {};
    accA = __builtin_amdgcn_mfma_f32_32x32x16_bf16(aqA[0], bk0, accA, 0, 0, 0);
    accA = __builtin_amdgcn_mfma_f32_32x32x16_bf16(aqA[1], bk1, accA, 0, 0, 0);
    accA = __builtin_amdgcn_mfma_f32_32x32x16_bf16(aqA[2], bk2, accA, 0, 0, 0);
    accA = __builtin_amdgcn_mfma_f32_32x32x16_bf16(aqA[3], bk3, accA, 0, 0, 0);
    accB = __builtin_amdgcn_mfma_f32_32x32x16_bf16(aqB[0], bk0, accB, 0, 0, 0);
    accB = __builtin_amdgcn_mfma_f32_32x32x16_bf16(aqB[1], bk1, accB, 0, 0, 0);
    accB = __builtin_amdgcn_mfma_f32_32x32x16_bf16(aqB[2], bk2, accB, 0, 0, 0);
    accB = __builtin_amdgcn_mfma_f32_32x32x16_bf16(aqB[3], bk3, accB, 0, 0, 0);
#pragma unroll
    for (int r = 0; r < 16; ++r) {
      obA[(size_t)((r & 3) + 8 * (r >> 2)) * TT + nc * 32] =
          __builtin_amdgcn_exp2f(accA[r] + sA[r]);
    }
#pragma unroll
    for (int r = 0; r < 16; ++r) sB[r] += __builtin_amdgcn_exp2f(accB[r]);
  }

#pragma unroll
  for (int r = 0; r < 16; ++r) {
    float sr = sB[r];
    sr += __shfl_xor(sr, 1);
    sr += __shfl_xor(sr, 2);
    sr += __shfl_xor(sr, 4);
    sr += __shfl_xor(sr, 8);
    sr += __shfl_xor(sr, 16);
    sB[r] = -__builtin_amdgcn_logf(sr);
  }

  // ---- final: pass 2 (B) ----
  for (int nc = 0; nc < 64; ++nc) {
    const bf16* kp = kb + (size_t)nc * 2048;
    bf16x8 bk0 = *reinterpret_cast<const bf16x8*>(kp);
    bf16x8 bk1 = *reinterpret_cast<const bf16x8*>(kp + 512);
    bf16x8 bk2 = *reinterpret_cast<const bf16x8*>(kp + 1024);
    bf16x8 bk3 = *reinterpret_cast<const bf16x8*>(kp + 1536);
    f32x16 acc = {};
    acc = __builtin_amdgcn_mfma_f32_32x32x16_bf16(aqB[0], bk0, acc, 0, 0, 0);
    acc = __builtin_amdgcn_mfma_f32_32x32x16_bf16(aqB[1], bk1, acc, 0, 0, 0);
    acc = __builtin_amdgcn_mfma_f32_32x32x16_bf16(aqB[2], bk2, acc, 0, 0, 0);
    acc = __builtin_amdgcn_mfma_f32_32x32x16_bf16(aqB[3], bk3, acc, 0, 0, 0);
#pragma unroll
    for (int r = 0; r < 16; ++r) {
      obB[(size_t)((r & 3) + 8 * (r >> 2)) * TT + nc * 32] =
          __builtin_amdgcn_exp2f(acc[r] + sB[r]);
    }
  }
}

extern "C" void kernel_launch(void* const* d_in, const int* in_sizes, int n_in,
                              void* d_out, int out_size, void* d_ws, size_t ws_size,
                              hipStream_t stream) {
  // inputs: v,k,q, wq_w,wq_b, wk_w,wk_b, wv_w,wv_b, dense_w,dense_b, fc_w,fc_b
  const float* k_in = (const float*)d_in[1];
  const float* q_in = (const float*)d_in[2];
  const float* wq_w = (const float*)d_in[3];
  const float* wq_b = (const float*)d_in[4];
  const float* wk_w = (const float*)d_in[5];
  const float* wk_b = (const float*)d_in[6];
  float* out = (float*)d_out;

  // ws layout (bf16): qbf,kbf [8192x1024], w2 [2048x1024], Qp,Kp permuted [8192x1024]
  bf16* qbf  = (bf16*)d_ws;
  bf16* kbf  = qbf  + (size_t)NTOK * DM;
  bf16* w2   = kbf  + (size_t)NTOK * DM;     // wq rows then wk rows
  bf16* Qp   = w2   + (size_t)2 * DM * DM;
  bf16* Kp   = Qp   + (size_t)NTOK * DM;

  const int prep_blocks = (2 * N4_QK + 2 * N4_W + N4_ONES) / 256;  // 18440
  prep_k<<<prep_blocks, 256, 0, stream>>>(q_in, k_in, wq_w, wk_w, qbf, out);

  gemm_qk<<<1024, 256, 0, stream>>>(qbf, kbf, w2, wq_b, wk_b, Qp, Kp);

  dim3 ag(TT / 256, 4 * NH);
  attn3_k<<<ag, 256, 0, stream>>>(Qp, Kp, out + 8192);
}

// Round 5
// 347.309 us; speedup vs baseline: 1.2303x; 1.2303x over previous
//
#include <hip/hip_runtime.h>
#include <hip/hip_bf16.h>

#define NTOK 8192   // B*T
#define DM   1024
#define TT   2048
#define NH   16
#define BH_STRIDE (TT * 64)   // 131072 elems per (b,h) in permuted Q/K

typedef __hip_bfloat16 bf16;
typedef short bf16x8 __attribute__((ext_vector_type(8)));
typedef float f32x4  __attribute__((ext_vector_type(4)));
typedef float f32x16 __attribute__((ext_vector_type(16)));

#define N4_QK 2097152   // 8192*1024/4
#define N4_W  262144    // 1024*1024/4
#define N4_ONES 2048    // 8192/4

__device__ __forceinline__ void gload_lds16(const void* g, void* l) {
  __builtin_amdgcn_global_load_lds(
      (const __attribute__((address_space(1))) unsigned int*)g,
      (__attribute__((address_space(3))) unsigned int*)l, 16, 0, 0);
}

// ---- fused fp32->bf16 cvt (q,k,wq,wk -> contiguous bf16 ws) + ones for out0 ----
__global__ void prep_k(const float* __restrict__ q, const float* __restrict__ k,
                       const float* __restrict__ wq, const float* __restrict__ wk,
                       bf16* __restrict__ dst, float* __restrict__ ones) {
  const int i = blockIdx.x * 256 + threadIdx.x;
  const int total_cvt = 2 * N4_QK + 2 * N4_W;
  if (i < total_cvt) {
    const float* src;
    if (i < N4_QK)            src = q  + (size_t)i * 4;
    else if (i < 2 * N4_QK)   src = k  + (size_t)(i - N4_QK) * 4;
    else if (i < 2 * N4_QK + N4_W) src = wq + (size_t)(i - 2 * N4_QK) * 4;
    else                      src = wk + (size_t)(i - 2 * N4_QK - N4_W) * 4;
    float4 v = *reinterpret_cast<const float4*>(src);
    bf16 o[4] = {__float2bfloat16(v.x), __float2bfloat16(v.y),
                 __float2bfloat16(v.z), __float2bfloat16(v.w)};
    reinterpret_cast<ushort4*>(dst)[i] = *reinterpret_cast<ushort4*>(o);
  } else {
    const int j = i - total_cvt;          // 0..2047
    reinterpret_cast<float4*>(ones)[j] = make_float4(1.f, 1.f, 1.f, 1.f);
  }
}

// ---- merged projection GEMM, epilogue writes PERMUTED fragment-native layout ----
// Qp/Kp[(b*16+h)][tc(64)][t(4)][lh(2)][tk(32)][e(8)]: element (tok,d) at
// tc=tok>>5, tk=tok&31, t=d>>4, lh=(d>>3)&1, e=d&7.
__global__ void gemm_qk(const bf16* __restrict__ Aq, const bf16* __restrict__ Ak,
                        const bf16* __restrict__ W,
                        const float* __restrict__ bq, const float* __restrict__ bk,
                        bf16* __restrict__ Qp, bf16* __restrict__ Kp)
{
  __shared__ bf16 sA[128 * 64];
  __shared__ bf16 sB[128 * 64];
  const int tid  = threadIdx.x;
  const int lane = tid & 63;
  const int wave = tid >> 6;
  const int bm   = (blockIdx.x >> 4) << 7;
  const int bn   = (blockIdx.x & 15) << 7;
  const bool isQ = bn < 1024;
  const bf16* __restrict__ A = isQ ? Aq : Ak;
  const float scale = isQ ? 0.18033688011112042f : 1.0f;  // log2(e)/8
  const float* __restrict__ bias = isQ ? bq : (bk - 1024);
  bf16* __restrict__ dst = isQ ? Qp : Kp;

  const int wr   = (wave >> 1) << 6;
  const int wc   = (wave & 1) << 6;
  const int lrow = lane & 15;
  const int lk8  = (lane >> 4) << 3;
  const int trow = tid >> 3;
  const int tcol = (tid & 7) << 3;

  f32x4 acc[4][4] = {};

  for (int k0 = 0; k0 < 1024; k0 += 64) {
#pragma unroll
    for (int i = 0; i < 4; ++i) {
      const int r = trow + i * 32;
      gload_lds16(A + (size_t)(bm + r) * 1024 + k0 + tcol, sA + r * 64 + tcol);
      gload_lds16(W + (size_t)(bn + r) * 1024 + k0 + tcol, sB + r * 64 + tcol);
    }
    __syncthreads();

    bf16x8 af[4][2], bfr[4][2];
#pragma unroll
    for (int mi = 0; mi < 4; ++mi) {
      af[mi][0]  = *reinterpret_cast<const bf16x8*>(sA + (wr + mi * 16 + lrow) * 64 + lk8);
      af[mi][1]  = *reinterpret_cast<const bf16x8*>(sA + (wr + mi * 16 + lrow) * 64 + 32 + lk8);
      bfr[mi][0] = *reinterpret_cast<const bf16x8*>(sB + (wc + mi * 16 + lrow) * 64 + lk8);
      bfr[mi][1] = *reinterpret_cast<const bf16x8*>(sB + (wc + mi * 16 + lrow) * 64 + 32 + lk8);
    }
#pragma unroll
    for (int mi = 0; mi < 4; ++mi)
#pragma unroll
      for (int ni = 0; ni < 4; ++ni) {
        acc[mi][ni] = __builtin_amdgcn_mfma_f32_16x16x32_bf16(af[mi][0], bfr[ni][0], acc[mi][ni], 0, 0, 0);
        acc[mi][ni] = __builtin_amdgcn_mfma_f32_16x16x32_bf16(af[mi][1], bfr[ni][1], acc[mi][ni], 0, 0, 0);
      }
    __syncthreads();
  }

#pragma unroll
  for (int mi = 0; mi < 4; ++mi)
#pragma unroll
    for (int ni = 0; ni < 4; ++ni) {
      const int col = bn + wc + ni * 16 + lrow;          // global feature 0..2047
      const float bv = bias[col];
      const int d  = col & 63;
      const int hh = (col >> 6) & 15;
      const size_t doff = (size_t)((d >> 4) * 2 + ((d >> 3) & 1)) * 256 + (d & 7);
#pragma unroll
      for (int j = 0; j < 4; ++j) {
        const int row = bm + wr + mi * 16 + ((lane >> 4) << 2) + j;  // token 0..8191
        const int bb  = row >> 11;
        const int tok = row & (TT - 1);
        const size_t idx = (size_t)(bb * NH + hh) * BH_STRIDE
                         + (size_t)(tok >> 5) * 2048 + doff + (size_t)(tok & 31) * 8;
        dst[idx] = __float2bfloat16((acc[mi][ni][j] + bv) * scale);
      }
    }
}

// ---- pass 1 kernel: row sums of exp2(QK^T), writes -log2(sum) per row ----
// 1D grid 1024: bh = bid & 63 (XCD-local K panels), tile = bid >> 6.
__global__ __launch_bounds__(256, 4) void attn_sum_k(
    const bf16* __restrict__ Qp, const bf16* __restrict__ Kp, float* __restrict__ sums)
{
  const int lane = threadIdx.x & 63;
  const int wave = threadIdx.x >> 6;
  const int l31  = lane & 31;
  const int lh   = lane >> 5;
  const int bh   = blockIdx.x & 63;
  const int tc   = (blockIdx.x >> 6) * 4 + wave;   // 0..63
  const int q0   = tc * 32;

  const bf16* qb = Qp + (size_t)bh * BH_STRIDE + (size_t)tc * 2048 + lh * 256 + l31 * 8;
  bf16x8 aq[4];
#pragma unroll
  for (int t = 0; t < 4; ++t)
    aq[t] = *reinterpret_cast<const bf16x8*>(qb + t * 512);

  const bf16* kb = Kp + (size_t)bh * BH_STRIDE + lh * 256 + l31 * 8;

  float s[16];
#pragma unroll
  for (int r = 0; r < 16; ++r) s[r] = 0.f;

  for (int nc = 0; nc < 64; ++nc) {
    const bf16* kp = kb + (size_t)nc * 2048;
    bf16x8 bk0 = *reinterpret_cast<const bf16x8*>(kp);
    bf16x8 bk1 = *reinterpret_cast<const bf16x8*>(kp + 512);
    bf16x8 bk2 = *reinterpret_cast<const bf16x8*>(kp + 1024);
    bf16x8 bk3 = *reinterpret_cast<const bf16x8*>(kp + 1536);
    f32x16 acc = {};
    acc = __builtin_amdgcn_mfma_f32_32x32x16_bf16(aq[0], bk0, acc, 0, 0, 0);
    acc = __builtin_amdgcn_mfma_f32_32x32x16_bf16(aq[1], bk1, acc, 0, 0, 0);
    acc = __builtin_amdgcn_mfma_f32_32x32x16_bf16(aq[2], bk2, acc, 0, 0, 0);
    acc = __builtin_amdgcn_mfma_f32_32x32x16_bf16(aq[3], bk3, acc, 0, 0, 0);
#pragma unroll
    for (int r = 0; r < 16; ++r) s[r] += __builtin_amdgcn_exp2f(acc[r]);
  }

  const int rowbase = bh * TT + q0 + 4 * lh;
#pragma unroll
  for (int r = 0; r < 16; ++r) {
    float sr = s[r];
    sr += __shfl_xor(sr, 1);
    sr += __shfl_xor(sr, 2);
    sr += __shfl_xor(sr, 4);
    sr += __shfl_xor(sr, 8);
    sr += __shfl_xor(sr, 16);
    const float v = -__builtin_amdgcn_logf(sr);   // -log2(sum)
    if (l31 == r) sums[rowbase + (r & 3) + 8 * (r >> 2)] = v;
  }
}

// ---- pass 2 kernel: recompute QK^T, write exp2(acc - log2(sum)) nt ----
__global__ __launch_bounds__(256, 4) void attn_wr_k(
    const bf16* __restrict__ Qp, const bf16* __restrict__ Kp,
    const float* __restrict__ sums, float* __restrict__ attn)
{
  const int lane = threadIdx.x & 63;
  const int wave = threadIdx.x >> 6;
  const int l31  = lane & 31;
  const int lh   = lane >> 5;
  const int bh   = blockIdx.x & 63;
  const int tc   = (blockIdx.x >> 6) * 4 + wave;
  const int q0   = tc * 32;

  const bf16* qb = Qp + (size_t)bh * BH_STRIDE + (size_t)tc * 2048 + lh * 256 + l31 * 8;
  bf16x8 aq[4];
#pragma unroll
  for (int t = 0; t < 4; ++t)
    aq[t] = *reinterpret_cast<const bf16x8*>(qb + t * 512);

  const bf16* kb = Kp + (size_t)bh * BH_STRIDE + lh * 256 + l31 * 8;

  float sA[16];
  const int rowbase = bh * TT + q0 + 4 * lh;
#pragma unroll
  for (int r = 0; r < 16; ++r)
    sA[r] = sums[rowbase + (r & 3) + 8 * (r >> 2)];

  float* obase = attn + ((size_t)bh * TT + q0 + 4 * lh) * TT + l31;

  for (int nc = 0; nc < 64; ++nc) {
    const bf16* kp = kb + (size_t)nc * 2048;
    bf16x8 bk0 = *reinterpret_cast<const bf16x8*>(kp);
    bf16x8 bk1 = *reinterpret_cast<const bf16x8*>(kp + 512);
    bf16x8 bk2 = *reinterpret_cast<const bf16x8*>(kp + 1024);
    bf16x8 bk3 = *reinterpret_cast<const bf16x8*>(kp + 1536);
    f32x16 acc = {};
    acc = __builtin_amdgcn_mfma_f32_32x32x16_bf16(aq[0], bk0, acc, 0, 0, 0);
    acc = __builtin_amdgcn_mfma_f32_32x32x16_bf16(aq[1], bk1, acc, 0, 0, 0);
    acc = __builtin_amdgcn_mfma_f32_32x32x16_bf16(aq[2], bk2, acc, 0, 0, 0);
    acc = __builtin_amdgcn_mfma_f32_32x32x16_bf16(aq[3], bk3, acc, 0, 0, 0);
#pragma unroll
    for (int r = 0; r < 16; ++r) {
      const float p = __builtin_amdgcn_exp2f(acc[r] + sA[r]);
      __builtin_nontemporal_store(p, obase + (size_t)((r & 3) + 8 * (r >> 2)) * TT + nc * 32);
    }
  }
}

extern "C" void kernel_launch(void* const* d_in, const int* in_sizes, int n_in,
                              void* d_out, int out_size, void* d_ws, size_t ws_size,
                              hipStream_t stream) {
  // inputs: v,k,q, wq_w,wq_b, wk_w,wk_b, wv_w,wv_b, dense_w,dense_b, fc_w,fc_b
  const float* k_in = (const float*)d_in[1];
  const float* q_in = (const float*)d_in[2];
  const float* wq_w = (const float*)d_in[3];
  const float* wq_b = (const float*)d_in[4];
  const float* wk_w = (const float*)d_in[5];
  const float* wk_b = (const float*)d_in[6];
  float* out = (float*)d_out;

  // ws layout (bf16): qbf,kbf [8192x1024], w2 [2048x1024], Qp,Kp permuted, sums f32[64*2048]
  bf16* qbf  = (bf16*)d_ws;
  bf16* kbf  = qbf  + (size_t)NTOK * DM;
  bf16* w2   = kbf  + (size_t)NTOK * DM;     // wq rows then wk rows
  bf16* Qp   = w2   + (size_t)2 * DM * DM;
  bf16* Kp   = Qp   + (size_t)NTOK * DM;
  float* sums = (float*)(Kp + (size_t)NTOK * DM);

  const int prep_blocks = (2 * N4_QK + 2 * N4_W + N4_ONES) / 256;  // 18440
  prep_k<<<prep_blocks, 256, 0, stream>>>(q_in, k_in, wq_w, wk_w, qbf, out);

  gemm_qk<<<1024, 256, 0, stream>>>(qbf, kbf, w2, wq_b, wk_b, Qp, Kp);

  attn_sum_k<<<1024, 256, 0, stream>>>(Qp, Kp, sums);
  attn_wr_k<<<1024, 256, 0, stream>>>(Qp, Kp, sums, out + 8192);
}

// Round 6
// 344.457 us; speedup vs baseline: 1.2405x; 1.0083x over previous
//
#include <hip/hip_runtime.h>
#include <hip/hip_bf16.h>

#define NTOK 8192   // B*T
#define DM   1024
#define TT   2048
#define NH   16
#define BH_STRIDE (TT * 64)   // 131072 elems per (b,h) in permuted Q/K

typedef __hip_bfloat16 bf16;
typedef short bf16x8 __attribute__((ext_vector_type(8)));
typedef float f32x4  __attribute__((ext_vector_type(4)));
typedef float f32x16 __attribute__((ext_vector_type(16)));

#define N4_QK 2097152   // 8192*1024/4
#define N4_W  262144    // 1024*1024/4
#define N4_ONES 2048    // 8192/4

__device__ __forceinline__ void gload_lds16(const void* g, void* l) {
  __builtin_amdgcn_global_load_lds(
      (const __attribute__((address_space(1))) unsigned int*)g,
      (__attribute__((address_space(3))) unsigned int*)l, 16, 0, 0);
}

// ---- fused fp32->bf16 cvt (q,k,wq,wk -> contiguous bf16 ws) + ones for out0 ----
__global__ void prep_k(const float* __restrict__ q, const float* __restrict__ k,
                       const float* __restrict__ wq, const float* __restrict__ wk,
                       bf16* __restrict__ dst, float* __restrict__ ones) {
  const int i = blockIdx.x * 256 + threadIdx.x;
  const int total_cvt = 2 * N4_QK + 2 * N4_W;
  if (i < total_cvt) {
    const float* src;
    if (i < N4_QK)            src = q  + (size_t)i * 4;
    else if (i < 2 * N4_QK)   src = k  + (size_t)(i - N4_QK) * 4;
    else if (i < 2 * N4_QK + N4_W) src = wq + (size_t)(i - 2 * N4_QK) * 4;
    else                      src = wk + (size_t)(i - 2 * N4_QK - N4_W) * 4;
    float4 v = *reinterpret_cast<const float4*>(src);
    bf16 o[4] = {__float2bfloat16(v.x), __float2bfloat16(v.y),
                 __float2bfloat16(v.z), __float2bfloat16(v.w)};
    reinterpret_cast<ushort4*>(dst)[i] = *reinterpret_cast<ushort4*>(o);
  } else {
    const int j = i - total_cvt;          // 0..2047
    reinterpret_cast<float4*>(ones)[j] = make_float4(1.f, 1.f, 1.f, 1.f);
  }
}

// ---- merged projection GEMM, LDS-staged permuted epilogue ----
// Qp/Kp[(b*16+h)][tc(64)][t(4)][lh(2)][tk(32)][e(8)]: element (tok,d) at
// tc=tok>>5, tk=tok&31, t=d>>4, lh=(d>>3)&1, e=d&7.
// Per 128x128 tile the permuted output is 2 contiguous 16KB regions (2 heads
// x 4 whole token-chunks) -> stage in LDS, stream out coalesced 16B/thread.
__global__ void gemm_qk(const bf16* __restrict__ Aq, const bf16* __restrict__ Ak,
                        const bf16* __restrict__ W,
                        const float* __restrict__ bq, const float* __restrict__ bk,
                        bf16* __restrict__ Qp, bf16* __restrict__ Kp)
{
  __shared__ bf16 sm[16384];          // 32KB: sA | sB during K-loop, permuted tile in epilogue
  bf16* sA = sm;
  bf16* sB = sm + 8192;
  const int tid  = threadIdx.x;
  const int lane = tid & 63;
  const int wave = tid >> 6;
  const int bm   = (blockIdx.x >> 4) << 7;
  const int bn   = (blockIdx.x & 15) << 7;
  const bool isQ = bn < 1024;
  const bf16* __restrict__ A = isQ ? Aq : Ak;
  const float scale = isQ ? 0.18033688011112042f : 1.0f;  // log2(e)/8
  const float* __restrict__ bias = isQ ? bq : (bk - 1024);
  bf16* __restrict__ dst = isQ ? Qp : Kp;

  const int wr   = (wave >> 1) << 6;
  const int wc   = (wave & 1) << 6;
  const int lrow = lane & 15;
  const int lk8  = (lane >> 4) << 3;
  const int trow = tid >> 3;
  const int tcol = (tid & 7) << 3;

  f32x4 acc[4][4] = {};

  for (int k0 = 0; k0 < 1024; k0 += 64) {
#pragma unroll
    for (int i = 0; i < 4; ++i) {
      const int r = trow + i * 32;
      gload_lds16(A + (size_t)(bm + r) * 1024 + k0 + tcol, sA + r * 64 + tcol);
      gload_lds16(W + (size_t)(bn + r) * 1024 + k0 + tcol, sB + r * 64 + tcol);
    }
    __syncthreads();

    bf16x8 af[4][2], bfr[4][2];
#pragma unroll
    for (int mi = 0; mi < 4; ++mi) {
      af[mi][0]  = *reinterpret_cast<const bf16x8*>(sA + (wr + mi * 16 + lrow) * 64 + lk8);
      af[mi][1]  = *reinterpret_cast<const bf16x8*>(sA + (wr + mi * 16 + lrow) * 64 + 32 + lk8);
      bfr[mi][0] = *reinterpret_cast<const bf16x8*>(sB + (wc + mi * 16 + lrow) * 64 + lk8);
      bfr[mi][1] = *reinterpret_cast<const bf16x8*>(sB + (wc + mi * 16 + lrow) * 64 + 32 + lk8);
    }
#pragma unroll
    for (int mi = 0; mi < 4; ++mi)
#pragma unroll
      for (int ni = 0; ni < 4; ++ni) {
        acc[mi][ni] = __builtin_amdgcn_mfma_f32_16x16x32_bf16(af[mi][0], bfr[ni][0], acc[mi][ni], 0, 0, 0);
        acc[mi][ni] = __builtin_amdgcn_mfma_f32_16x16x32_bf16(af[mi][1], bfr[ni][1], acc[mi][ni], 0, 0, 0);
      }
    __syncthreads();
  }

  // ---- epilogue: bias+scale+cvt into LDS in permuted order ----
#pragma unroll
  for (int mi = 0; mi < 4; ++mi)
#pragma unroll
    for (int ni = 0; ni < 4; ++ni) {
      const int col = bn + wc + ni * 16 + lrow;          // global feature 0..2047
      const float bv = bias[col];
      const int d  = col & 63;
      const int hp = (col >> 6) & 1;                     // which of the tile's 2 heads
      const int doff = ((d >> 4) * 2 + ((d >> 3) & 1)) * 256 + (d & 7);
#pragma unroll
      for (int j = 0; j < 4; ++j) {
        const int tokL = wr + mi * 16 + ((lane >> 4) << 2) + j;   // 0..127
        sm[hp * 8192 + ((tokL >> 5) << 11) + doff + ((tokL & 31) << 3)] =
            __float2bfloat16((acc[mi][ni][j] + bv) * scale);
      }
    }
  __syncthreads();

  // ---- coalesced stream-out: 2 heads x 16KB contiguous ----
  const int bb  = bm >> 11;
  const int hh0 = (bn >> 6) & 15;
  const size_t tc0 = (size_t)((bm & 2047) >> 5);
  const size_t g0 = (size_t)(bb * NH + hh0)     * BH_STRIDE + tc0 * 2048;
  const size_t g1 = (size_t)(bb * NH + hh0 + 1) * BH_STRIDE + tc0 * 2048;
#pragma unroll
  for (int rr = 0; rr < 4; ++rr) {
    const int off = rr * 2048 + tid * 8;
    *reinterpret_cast<ulonglong2*>(dst + g0 + off) =
        *reinterpret_cast<const ulonglong2*>(sm + off);
    *reinterpret_cast<ulonglong2*>(dst + g1 + off) =
        *reinterpret_cast<const ulonglong2*>(sm + 8192 + off);
  }
}

// ---- pass 1 kernel: row sums of exp2(QK^T), writes -log2(sum) per row ----
// 1D grid 1024: bh = bid & 63 (XCD-local K panels), tile = bid >> 6.
__global__ __launch_bounds__(256, 4) void attn_sum_k(
    const bf16* __restrict__ Qp, const bf16* __restrict__ Kp, float* __restrict__ sums)
{
  const int lane = threadIdx.x & 63;
  const int wave = threadIdx.x >> 6;
  const int l31  = lane & 31;
  const int lh   = lane >> 5;
  const int bh   = blockIdx.x & 63;
  const int tc   = (blockIdx.x >> 6) * 4 + wave;   // 0..63
  const int q0   = tc * 32;

  const bf16* qb = Qp + (size_t)bh * BH_STRIDE + (size_t)tc * 2048 + lh * 256 + l31 * 8;
  bf16x8 aq[4];
#pragma unroll
  for (int t = 0; t < 4; ++t)
    aq[t] = *reinterpret_cast<const bf16x8*>(qb + t * 512);

  const bf16* kb = Kp + (size_t)bh * BH_STRIDE + lh * 256 + l31 * 8;

  float s[16];
#pragma unroll
  for (int r = 0; r < 16; ++r) s[r] = 0.f;

  for (int nc = 0; nc < 64; ++nc) {
    const bf16* kp = kb + (size_t)nc * 2048;
    bf16x8 bk0 = *reinterpret_cast<const bf16x8*>(kp);
    bf16x8 bk1 = *reinterpret_cast<const bf16x8*>(kp + 512);
    bf16x8 bk2 = *reinterpret_cast<const bf16x8*>(kp + 1024);
    bf16x8 bk3 = *reinterpret_cast<const bf16x8*>(kp + 1536);
    f32x16 acc = {};
    acc = __builtin_amdgcn_mfma_f32_32x32x16_bf16(aq[0], bk0, acc, 0, 0, 0);
    acc = __builtin_amdgcn_mfma_f32_32x32x16_bf16(aq[1], bk1, acc, 0, 0, 0);
    acc = __builtin_amdgcn_mfma_f32_32x32x16_bf16(aq[2], bk2, acc, 0, 0, 0);
    acc = __builtin_amdgcn_mfma_f32_32x32x16_bf16(aq[3], bk3, acc, 0, 0, 0);
#pragma unroll
    for (int r = 0; r < 16; ++r) s[r] += __builtin_amdgcn_exp2f(acc[r]);
  }

  const int rowbase = bh * TT + q0 + 4 * lh;
#pragma unroll
  for (int r = 0; r < 16; ++r) {
    float sr = s[r];
    sr += __shfl_xor(sr, 1);
    sr += __shfl_xor(sr, 2);
    sr += __shfl_xor(sr, 4);
    sr += __shfl_xor(sr, 8);
    sr += __shfl_xor(sr, 16);
    const float v = -__builtin_amdgcn_logf(sr);   // -log2(sum)
    if (l31 == r) sums[rowbase + (r & 3) + 8 * (r >> 2)] = v;
  }
}

// ---- pass 2 kernel: recompute QK^T, write exp2(acc - log2(sum)) nt ----
__global__ __launch_bounds__(256, 4) void attn_wr_k(
    const bf16* __restrict__ Qp, const bf16* __restrict__ Kp,
    const float* __restrict__ sums, float* __restrict__ attn)
{
  const int lane = threadIdx.x & 63;
  const int wave = threadIdx.x >> 6;
  const int l31  = lane & 31;
  const int lh   = lane >> 5;
  const int bh   = blockIdx.x & 63;
  const int tc   = (blockIdx.x >> 6) * 4 + wave;
  const int q0   = tc * 32;

  const bf16* qb = Qp + (size_t)bh * BH_STRIDE + (size_t)tc * 2048 + lh * 256 + l31 * 8;
  bf16x8 aq[4];
#pragma unroll
  for (int t = 0; t < 4; ++t)
    aq[t] = *reinterpret_cast<const bf16x8*>(qb + t * 512);

  const bf16* kb = Kp + (size_t)bh * BH_STRIDE + lh * 256 + l31 * 8;

  float sA[16];
  const int rowbase = bh * TT + q0 + 4 * lh;
#pragma unroll
  for (int r = 0; r < 16; ++r)
    sA[r] = sums[rowbase + (r & 3) + 8 * (r >> 2)];

  float* obase = attn + ((size_t)bh * TT + q0 + 4 * lh) * TT + l31;

  for (int nc = 0; nc < 64; ++nc) {
    const bf16* kp = kb + (size_t)nc * 2048;
    bf16x8 bk0 = *reinterpret_cast<const bf16x8*>(kp);
    bf16x8 bk1 = *reinterpret_cast<const bf16x8*>(kp + 512);
    bf16x8 bk2 = *reinterpret_cast<const bf16x8*>(kp + 1024);
    bf16x8 bk3 = *reinterpret_cast<const bf16x8*>(kp + 1536);
    f32x16 acc = {};
    acc = __builtin_amdgcn_mfma_f32_32x32x16_bf16(aq[0], bk0, acc, 0, 0, 0);
    acc = __builtin_amdgcn_mfma_f32_32x32x16_bf16(aq[1], bk1, acc, 0, 0, 0);
    acc = __builtin_amdgcn_mfma_f32_32x32x16_bf16(aq[2], bk2, acc, 0, 0, 0);
    acc = __builtin_amdgcn_mfma_f32_32x32x16_bf16(aq[3], bk3, acc, 0, 0, 0);
#pragma unroll
    for (int r = 0; r < 16; ++r) {
      const float p = __builtin_amdgcn_exp2f(acc[r] + sA[r]);
      __builtin_nontemporal_store(p, obase + (size_t)((r & 3) + 8 * (r >> 2)) * TT + nc * 32);
    }
  }
}

extern "C" void kernel_launch(void* const* d_in, const int* in_sizes, int n_in,
                              void* d_out, int out_size, void* d_ws, size_t ws_size,
                              hipStream_t stream) {
  // inputs: v,k,q, wq_w,wq_b, wk_w,wk_b, wv_w,wv_b, dense_w,dense_b, fc_w,fc_b
  const float* k_in = (const float*)d_in[1];
  const float* q_in = (const float*)d_in[2];
  const float* wq_w = (const float*)d_in[3];
  const float* wq_b = (const float*)d_in[4];
  const float* wk_w = (const float*)d_in[5];
  const float* wk_b = (const float*)d_in[6];
  float* out = (float*)d_out;

  // ws layout (bf16): qbf,kbf [8192x1024], w2 [2048x1024], Qp,Kp permuted, sums f32[64*2048]
  bf16* qbf  = (bf16*)d_ws;
  bf16* kbf  = qbf  + (size_t)NTOK * DM;
  bf16* w2   = kbf  + (size_t)NTOK * DM;     // wq rows then wk rows
  bf16* Qp   = w2   + (size_t)2 * DM * DM;
  bf16* Kp   = Qp   + (size_t)NTOK * DM;
  float* sums = (float*)(Kp + (size_t)NTOK * DM);

  const int prep_blocks = (2 * N4_QK + 2 * N4_W + N4_ONES) / 256;  // 18440
  prep_k<<<prep_blocks, 256, 0, stream>>>(q_in, k_in, wq_w, wk_w, qbf, out);

  gemm_qk<<<1024, 256, 0, stream>>>(qbf, kbf, w2, wq_b, wk_b, Qp, Kp);

  attn_sum_k<<<1024, 256, 0, stream>>>(Qp, Kp, sums);
  attn_wr_k<<<1024, 256, 0, stream>>>(Qp, Kp, sums, out + 8192);
}

// Round 9
// 338.802 us; speedup vs baseline: 1.2612x; 1.0167x over previous
//
#include <hip/hip_runtime.h>
#include <hip/hip_bf16.h>

#define NTOK 8192   // B*T
#define DM   1024
#define TT   2048
#define NH   16
#define BH_STRIDE (TT * 64)   // 131072 elems per (b,h) in permuted Q/K

typedef __hip_bfloat16 bf16;
typedef short bf16x8 __attribute__((ext_vector_type(8)));
typedef float f32x4  __attribute__((ext_vector_type(4)));
typedef float f32x16 __attribute__((ext_vector_type(16)));

#define N4_QK 2097152   // 8192*1024/4
#define N4_W  262144    // 1024*1024/4
#define N4_ONES 2048    // 8192/4

__device__ __forceinline__ void gload_lds16(const void* g, void* l) {
  __builtin_amdgcn_global_load_lds(
      (const __attribute__((address_space(1))) unsigned int*)g,
      (__attribute__((address_space(3))) unsigned int*)l, 16, 0, 0);
}

// ---- fused fp32->bf16 cvt (q,k,wq,wk -> contiguous bf16 ws) + ones for out0 ----
__global__ void prep_k(const float* __restrict__ q, const float* __restrict__ k,
                       const float* __restrict__ wq, const float* __restrict__ wk,
                       bf16* __restrict__ dst, float* __restrict__ ones) {
  const int i = blockIdx.x * 256 + threadIdx.x;
  const int total_cvt = 2 * N4_QK + 2 * N4_W;
  if (i < total_cvt) {
    const float* src;
    if (i < N4_QK)            src = q  + (size_t)i * 4;
    else if (i < 2 * N4_QK)   src = k  + (size_t)(i - N4_QK) * 4;
    else if (i < 2 * N4_QK + N4_W) src = wq + (size_t)(i - 2 * N4_QK) * 4;
    else                      src = wk + (size_t)(i - 2 * N4_QK - N4_W) * 4;
    float4 v = *reinterpret_cast<const float4*>(src);
    bf16 o[4] = {__float2bfloat16(v.x), __float2bfloat16(v.y),
                 __float2bfloat16(v.z), __float2bfloat16(v.w)};
    reinterpret_cast<ushort4*>(dst)[i] = *reinterpret_cast<ushort4*>(o);
  } else {
    const int j = i - total_cvt;          // 0..2047
    reinterpret_cast<float4*>(ones)[j] = make_float4(1.f, 1.f, 1.f, 1.f);
  }
}

// ---- merged projection GEMM, LDS-staged permuted epilogue, XCD-swizzled ----
// Qp/Kp[(b*16+h)][tc(64)][t(4)][lh(2)][tk(32)][e(8)]: element (tok,d) at
// tc=tok>>5, tk=tok&31, t=d>>4, lh=(d>>3)&1, e=d&7.
__global__ void gemm_qk(const bf16* __restrict__ Aq, const bf16* __restrict__ Ak,
                        const bf16* __restrict__ W,
                        const float* __restrict__ bq, const float* __restrict__ bk,
                        bf16* __restrict__ Qp, bf16* __restrict__ Kp)
{
  __shared__ bf16 sm[16384];          // 32KB: sA | sB during K-loop, permuted tile in epilogue
  bf16* sA = sm;
  bf16* sB = sm + 8192;
  const int tid  = threadIdx.x;
  const int lane = tid & 63;
  const int wave = tid >> 6;
  // XCD-aware swizzle: each XCD owns 8 consecutive bm values x all 16 bn
  const int swz  = ((blockIdx.x & 7) << 7) | (blockIdx.x >> 3);
  const int bm   = (swz >> 4) << 7;
  const int bn   = (swz & 15) << 7;
  const bool isQ = bn < 1024;
  const bf16* __restrict__ A = isQ ? Aq : Ak;
  const float scale = isQ ? 0.18033688011112042f : 1.0f;  // log2(e)/8
  const float* __restrict__ bias = isQ ? bq : (bk - 1024);
  bf16* __restrict__ dst = isQ ? Qp : Kp;

  const int wr   = (wave >> 1) << 6;
  const int wc   = (wave & 1) << 6;
  const int lrow = lane & 15;
  const int lk8  = (lane >> 4) << 3;
  const int trow = tid >> 3;
  const int tcol = (tid & 7) << 3;

  f32x4 acc[4][4] = {};

  for (int k0 = 0; k0 < 1024; k0 += 64) {
#pragma unroll
    for (int i = 0; i < 4; ++i) {
      const int r = trow + i * 32;
      gload_lds16(A + (size_t)(bm + r) * 1024 + k0 + tcol, sA + r * 64 + tcol);
      gload_lds16(W + (size_t)(bn + r) * 1024 + k0 + tcol, sB + r * 64 + tcol);
    }
    __syncthreads();

    bf16x8 af[4][2], bfr[4][2];
#pragma unroll
    for (int mi = 0; mi < 4; ++mi) {
      af[mi][0]  = *reinterpret_cast<const bf16x8*>(sA + (wr + mi * 16 + lrow) * 64 + lk8);
      af[mi][1]  = *reinterpret_cast<const bf16x8*>(sA + (wr + mi * 16 + lrow) * 64 + 32 + lk8);
      bfr[mi][0] = *reinterpret_cast<const bf16x8*>(sB + (wc + mi * 16 + lrow) * 64 + lk8);
      bfr[mi][1] = *reinterpret_cast<const bf16x8*>(sB + (wc + mi * 16 + lrow) * 64 + 32 + lk8);
    }
#pragma unroll
    for (int mi = 0; mi < 4; ++mi)
#pragma unroll
      for (int ni = 0; ni < 4; ++ni) {
        acc[mi][ni] = __builtin_amdgcn_mfma_f32_16x16x32_bf16(af[mi][0], bfr[ni][0], acc[mi][ni], 0, 0, 0);
        acc[mi][ni] = __builtin_amdgcn_mfma_f32_16x16x32_bf16(af[mi][1], bfr[ni][1], acc[mi][ni], 0, 0, 0);
      }
    __syncthreads();
  }

  // ---- epilogue: bias+scale+cvt into LDS in permuted order ----
#pragma unroll
  for (int mi = 0; mi < 4; ++mi)
#pragma unroll
    for (int ni = 0; ni < 4; ++ni) {
      const int col = bn + wc + ni * 16 + lrow;          // global feature 0..2047
      const float bv = bias[col];
      const int d  = col & 63;
      const int hp = (col >> 6) & 1;                     // which of the tile's 2 heads
      const int doff = ((d >> 4) * 2 + ((d >> 3) & 1)) * 256 + (d & 7);
#pragma unroll
      for (int j = 0; j < 4; ++j) {
        const int tokL = wr + mi * 16 + ((lane >> 4) << 2) + j;   // 0..127
        sm[hp * 8192 + ((tokL >> 5) << 11) + doff + ((tokL & 31) << 3)] =
            __float2bfloat16((acc[mi][ni][j] + bv) * scale);
      }
    }
  __syncthreads();

  // ---- coalesced stream-out: 2 heads x 16KB contiguous ----
  const int bb  = bm >> 11;
  const int hh0 = (bn >> 6) & 15;
  const size_t tc0 = (size_t)((bm & 2047) >> 5);
  const size_t g0 = (size_t)(bb * NH + hh0)     * BH_STRIDE + tc0 * 2048;
  const size_t g1 = (size_t)(bb * NH + hh0 + 1) * BH_STRIDE + tc0 * 2048;
#pragma unroll
  for (int rr = 0; rr < 4; ++rr) {
    const int off = rr * 2048 + tid * 8;
    *reinterpret_cast<ulonglong2*>(dst + g0 + off) =
        *reinterpret_cast<const ulonglong2*>(sm + off);
    *reinterpret_cast<ulonglong2*>(dst + g1 + off) =
        *reinterpret_cast<const ulonglong2*>(sm + 8192 + off);
  }
}

// ---- pass 1 kernel: row sums of exp2(QK^T), writes -log2(sum) per row ----
// 1D grid 1024: bh = bid & 63 (XCD-local K panels), tile = bid >> 6.
__global__ __launch_bounds__(256, 4) void attn_sum_k(
    const bf16* __restrict__ Qp, const bf16* __restrict__ Kp, float* __restrict__ sums)
{
  const int lane = threadIdx.x & 63;
  const int wave = threadIdx.x >> 6;
  const int l31  = lane & 31;
  const int lh   = lane >> 5;
  const int bh   = blockIdx.x & 63;
  const int tc   = (blockIdx.x >> 6) * 4 + wave;   // 0..63
  const int q0   = tc * 32;

  const bf16* qb = Qp + (size_t)bh * BH_STRIDE + (size_t)tc * 2048 + lh * 256 + l31 * 8;
  bf16x8 aq[4];
#pragma unroll
  for (int t = 0; t < 4; ++t)
    aq[t] = *reinterpret_cast<const bf16x8*>(qb + t * 512);

  const bf16* kb = Kp + (size_t)bh * BH_STRIDE + lh * 256 + l31 * 8;

  float s[16];
#pragma unroll
  for (int r = 0; r < 16; ++r) s[r] = 0.f;

  for (int nc = 0; nc < 64; ++nc) {
    const bf16* kp = kb + (size_t)nc * 2048;
    bf16x8 bk0 = *reinterpret_cast<const bf16x8*>(kp);
    bf16x8 bk1 = *reinterpret_cast<const bf16x8*>(kp + 512);
    bf16x8 bk2 = *reinterpret_cast<const bf16x8*>(kp + 1024);
    bf16x8 bk3 = *reinterpret_cast<const bf16x8*>(kp + 1536);
    f32x16 acc = {};
    acc = __builtin_amdgcn_mfma_f32_32x32x16_bf16(aq[0], bk0, acc, 0, 0, 0);
    acc = __builtin_amdgcn_mfma_f32_32x32x16_bf16(aq[1], bk1, acc, 0, 0, 0);
    acc = __builtin_amdgcn_mfma_f32_32x32x16_bf16(aq[2], bk2, acc, 0, 0, 0);
    acc = __builtin_amdgcn_mfma_f32_32x32x16_bf16(aq[3], bk3, acc, 0, 0, 0);
#pragma unroll
    for (int r = 0; r < 16; ++r) s[r] += __builtin_amdgcn_exp2f(acc[r]);
  }

  const int rowbase = bh * TT + q0 + 4 * lh;
#pragma unroll
  for (int r = 0; r < 16; ++r) {
    float sr = s[r];
    sr += __shfl_xor(sr, 1);
    sr += __shfl_xor(sr, 2);
    sr += __shfl_xor(sr, 4);
    sr += __shfl_xor(sr, 8);
    sr += __shfl_xor(sr, 16);
    const float v = -__builtin_amdgcn_logf(sr);   // -log2(sum)
    if (l31 == r) sums[rowbase + (r & 3) + 8 * (r >> 2)] = v;
  }
}

// ---- pass 2 kernel: recompute QK^T, write exp2(acc - log2(sum)) nt ----
__global__ __launch_bounds__(256, 4) void attn_wr_k(
    const bf16* __restrict__ Qp, const bf16* __restrict__ Kp,
    const float* __restrict__ sums, float* __restrict__ attn)
{
  const int lane = threadIdx.x & 63;
  const int wave = threadIdx.x >> 6;
  const int l31  = lane & 31;
  const int lh   = lane >> 5;
  const int bh   = blockIdx.x & 63;
  const int tc   = (blockIdx.x >> 6) * 4 + wave;
  const int q0   = tc * 32;

  const bf16* qb = Qp + (size_t)bh * BH_STRIDE + (size_t)tc * 2048 + lh * 256 + l31 * 8;
  bf16x8 aq[4];
#pragma unroll
  for (int t = 0; t < 4; ++t)
    aq[t] = *reinterpret_cast<const bf16x8*>(qb + t * 512);

  const bf16* kb = Kp + (size_t)bh * BH_STRIDE + lh * 256 + l31 * 8;

  float sA[16];
  const int rowbase = bh * TT + q0 + 4 * lh;
#pragma unroll
  for (int r = 0; r < 16; ++r)
    sA[r] = sums[rowbase + (r & 3) + 8 * (r >> 2)];

  float* obase = attn + ((size_t)bh * TT + q0 + 4 * lh) * TT + l31;

  for (int nc = 0; nc < 64; ++nc) {
    const bf16* kp = kb + (size_t)nc * 2048;
    bf16x8 bk0 = *reinterpret_cast<const bf16x8*>(kp);
    bf16x8 bk1 = *reinterpret_cast<const bf16x8*>(kp + 512);
    bf16x8 bk2 = *reinterpret_cast<const bf16x8*>(kp + 1024);
    bf16x8 bk3 = *reinterpret_cast<const bf16x8*>(kp + 1536);
    f32x16 acc = {};
    acc = __builtin_amdgcn_mfma_f32_32x32x16_bf16(aq[0], bk0, acc, 0, 0, 0);
    acc = __builtin_amdgcn_mfma_f32_32x32x16_bf16(aq[1], bk1, acc, 0, 0, 0);
    acc = __builtin_amdgcn_mfma_f32_32x32x16_bf16(aq[2], bk2, acc, 0, 0, 0);
    acc = __builtin_amdgcn_mfma_f32_32x32x16_bf16(aq[3], bk3, acc, 0, 0, 0);
#pragma unroll
    for (int r = 0; r < 16; ++r) {
      const float p = __builtin_amdgcn_exp2f(acc[r] + sA[r]);
      __builtin_nontemporal_store(p, obase + (size_t)((r & 3) + 8 * (r >> 2)) * TT + nc * 32);
    }
  }
}

extern "C" void kernel_launch(void* const* d_in, const int* in_sizes, int n_in,
                              void* d_out, int out_size, void* d_ws, size_t ws_size,
                              hipStream_t stream) {
  // inputs: v,k,q, wq_w,wq_b, wk_w,wk_b, wv_w,wv_b, dense_w,dense_b, fc_w,fc_b
  const float* k_in = (const float*)d_in[1];
  const float* q_in = (const float*)d_in[2];
  const float* wq_w = (const float*)d_in[3];
  const float* wq_b = (const float*)d_in[4];
  const float* wk_w = (const float*)d_in[5];
  const float* wk_b = (const float*)d_in[6];
  float* out = (float*)d_out;

  // ws layout (bf16): qbf,kbf [8192x1024], w2 [2048x1024], Qp,Kp permuted, sums f32[64*2048]
  bf16* qbf  = (bf16*)d_ws;
  bf16* kbf  = qbf  + (size_t)NTOK * DM;
  bf16* w2   = kbf  + (size_t)NTOK * DM;     // wq rows then wk rows
  bf16* Qp   = w2   + (size_t)2 * DM * DM;
  bf16* Kp   = Qp   + (size_t)NTOK * DM;
  float* sums = (float*)(Kp + (size_t)NTOK * DM);

  const int prep_blocks = (2 * N4_QK + 2 * N4_W + N4_ONES) / 256;  // 18440
  prep_k<<<prep_blocks, 256, 0, stream>>>(q_in, k_in, wq_w, wk_w, qbf, out);

  gemm_qk<<<1024, 256, 0, stream>>>(qbf, kbf, w2, wq_b, wk_b, Qp, Kp);

  attn_sum_k<<<1024, 256, 0, stream>>>(Qp, Kp, sums);
  attn_wr_k<<<1024, 256, 0, stream>>>(Qp, Kp, sums, out + 8192);
}

// Round 11
// 325.301 us; speedup vs baseline: 1.3135x; 1.0415x over previous
//
#include <hip/hip_runtime.h>
#include <hip/hip_bf16.h>

#define NTOK 8192   // B*T
#define DM   1024
#define TT   2048
#define NH   16
#define BH_STRIDE (TT * 64)   // 131072 elems per (b,h) in permuted Q/K

typedef __hip_bfloat16 bf16;
typedef short bf16x8 __attribute__((ext_vector_type(8)));
typedef float f32x4  __attribute__((ext_vector_type(4)));
typedef float f32x16 __attribute__((ext_vector_type(16)));

#define N4_QK 2097152   // 8192*1024/4
#define N4_W  262144    // 1024*1024/4
#define N4_ONES 2048    // 8192/4

__device__ __forceinline__ void gload_lds16(const void* g, void* l) {
  __builtin_amdgcn_global_load_lds(
      (const __attribute__((address_space(1))) unsigned int*)g,
      (__attribute__((address_space(3))) unsigned int*)l, 16, 0, 0);
}

// ---- fused fp32->bf16 cvt (q,k,wq,wk -> contiguous bf16 ws) + ones for out0 ----
__global__ void prep_k(const float* __restrict__ q, const float* __restrict__ k,
                       const float* __restrict__ wq, const float* __restrict__ wk,
                       bf16* __restrict__ dst, float* __restrict__ ones) {
  const int i = blockIdx.x * 256 + threadIdx.x;
  const int total_cvt = 2 * N4_QK + 2 * N4_W;
  if (i < total_cvt) {
    const float* src;
    if (i < N4_QK)            src = q  + (size_t)i * 4;
    else if (i < 2 * N4_QK)   src = k  + (size_t)(i - N4_QK) * 4;
    else if (i < 2 * N4_QK + N4_W) src = wq + (size_t)(i - 2 * N4_QK) * 4;
    else                      src = wk + (size_t)(i - 2 * N4_QK - N4_W) * 4;
    float4 v = *reinterpret_cast<const float4*>(src);
    bf16 o[4] = {__float2bfloat16(v.x), __float2bfloat16(v.y),
                 __float2bfloat16(v.z), __float2bfloat16(v.w)};
    reinterpret_cast<ushort4*>(dst)[i] = *reinterpret_cast<ushort4*>(o);
  } else {
    const int j = i - total_cvt;          // 0..2047
    reinterpret_cast<float4*>(ones)[j] = make_float4(1.f, 1.f, 1.f, 1.f);
  }
}

// ---- merged projection GEMM, LDS-staged permuted epilogue, XCD-swizzled ----
// Qp/Kp[(b*16+h)][tc(64)][t(4)][lh(2)][tk(32)][e(8)]: element (tok,d) at
// tc=tok>>5, tk=tok&31, t=d>>4, lh=(d>>3)&1, e=d&7.
__global__ void gemm_qk(const bf16* __restrict__ Aq, const bf16* __restrict__ Ak,
                        const bf16* __restrict__ W,
                        const float* __restrict__ bq, const float* __restrict__ bk,
                        bf16* __restrict__ Qp, bf16* __restrict__ Kp)
{
  __shared__ bf16 sm[16384];          // 32KB: sA | sB during K-loop, permuted tile in epilogue
  bf16* sA = sm;
  bf16* sB = sm + 8192;
  const int tid  = threadIdx.x;
  const int lane = tid & 63;
  const int wave = tid >> 6;
  // XCD-aware swizzle: each XCD owns 8 consecutive bm values x all 16 bn
  const int swz  = ((blockIdx.x & 7) << 7) | (blockIdx.x >> 3);
  const int bm   = (swz >> 4) << 7;
  const int bn   = (swz & 15) << 7;
  const bool isQ = bn < 1024;
  const bf16* __restrict__ A = isQ ? Aq : Ak;
  const float scale = isQ ? 0.18033688011112042f : 1.0f;  // log2(e)/8
  const float* __restrict__ bias = isQ ? bq : (bk - 1024);
  bf16* __restrict__ dst = isQ ? Qp : Kp;

  const int wr   = (wave >> 1) << 6;
  const int wc   = (wave & 1) << 6;
  const int lrow = lane & 15;
  const int lk8  = (lane >> 4) << 3;
  const int trow = tid >> 3;
  const int tcol = (tid & 7) << 3;

  f32x4 acc[4][4] = {};

  for (int k0 = 0; k0 < 1024; k0 += 64) {
#pragma unroll
    for (int i = 0; i < 4; ++i) {
      const int r = trow + i * 32;
      gload_lds16(A + (size_t)(bm + r) * 1024 + k0 + tcol, sA + r * 64 + tcol);
      gload_lds16(W + (size_t)(bn + r) * 1024 + k0 + tcol, sB + r * 64 + tcol);
    }
    __syncthreads();

    bf16x8 af[4][2], bfr[4][2];
#pragma unroll
    for (int mi = 0; mi < 4; ++mi) {
      af[mi][0]  = *reinterpret_cast<const bf16x8*>(sA + (wr + mi * 16 + lrow) * 64 + lk8);
      af[mi][1]  = *reinterpret_cast<const bf16x8*>(sA + (wr + mi * 16 + lrow) * 64 + 32 + lk8);
      bfr[mi][0] = *reinterpret_cast<const bf16x8*>(sB + (wc + mi * 16 + lrow) * 64 + lk8);
      bfr[mi][1] = *reinterpret_cast<const bf16x8*>(sB + (wc + mi * 16 + lrow) * 64 + 32 + lk8);
    }
#pragma unroll
    for (int mi = 0; mi < 4; ++mi)
#pragma unroll
      for (int ni = 0; ni < 4; ++ni) {
        acc[mi][ni] = __builtin_amdgcn_mfma_f32_16x16x32_bf16(af[mi][0], bfr[ni][0], acc[mi][ni], 0, 0, 0);
        acc[mi][ni] = __builtin_amdgcn_mfma_f32_16x16x32_bf16(af[mi][1], bfr[ni][1], acc[mi][ni], 0, 0, 0);
      }
    __syncthreads();
  }

  // ---- epilogue: bias+scale+cvt into LDS in permuted order ----
#pragma unroll
  for (int mi = 0; mi < 4; ++mi)
#pragma unroll
    for (int ni = 0; ni < 4; ++ni) {
      const int col = bn + wc + ni * 16 + lrow;          // global feature 0..2047
      const float bv = bias[col];
      const int d  = col & 63;
      const int hp = (col >> 6) & 1;                     // which of the tile's 2 heads
      const int doff = ((d >> 4) * 2 + ((d >> 3) & 1)) * 256 + (d & 7);
#pragma unroll
      for (int j = 0; j < 4; ++j) {
        const int tokL = wr + mi * 16 + ((lane >> 4) << 2) + j;   // 0..127
        sm[hp * 8192 + ((tokL >> 5) << 11) + doff + ((tokL & 31) << 3)] =
            __float2bfloat16((acc[mi][ni][j] + bv) * scale);
      }
    }
  __syncthreads();

  // ---- coalesced stream-out: 2 heads x 16KB contiguous ----
  const int bb  = bm >> 11;
  const int hh0 = (bn >> 6) & 15;
  const size_t tc0 = (size_t)((bm & 2047) >> 5);
  const size_t g0 = (size_t)(bb * NH + hh0)     * BH_STRIDE + tc0 * 2048;
  const size_t g1 = (size_t)(bb * NH + hh0 + 1) * BH_STRIDE + tc0 * 2048;
#pragma unroll
  for (int rr = 0; rr < 4; ++rr) {
    const int off = rr * 2048 + tid * 8;
    *reinterpret_cast<ulonglong2*>(dst + g0 + off) =
        *reinterpret_cast<const ulonglong2*>(sm + off);
    *reinterpret_cast<ulonglong2*>(dst + g1 + off) =
        *reinterpret_cast<const ulonglong2*>(sm + 8192 + off);
  }
}

// ---- pass 1 kernel: row sums of exp2(QK^T), writes -log2(sum) per row ----
// 1D grid 1024: bh = bid & 63 (XCD-local K panels), tile = bid >> 6.
__global__ __launch_bounds__(256, 4) void attn_sum_k(
    const bf16* __restrict__ Qp, const bf16* __restrict__ Kp, float* __restrict__ sums)
{
  const int lane = threadIdx.x & 63;
  const int wave = threadIdx.x >> 6;
  const int l31  = lane & 31;
  const int lh   = lane >> 5;
  const int bh   = blockIdx.x & 63;
  const int tc   = (blockIdx.x >> 6) * 4 + wave;   // 0..63
  const int q0   = tc * 32;

  const bf16* qb = Qp + (size_t)bh * BH_STRIDE + (size_t)tc * 2048 + lh * 256 + l31 * 8;
  bf16x8 aq[4];
#pragma unroll
  for (int t = 0; t < 4; ++t)
    aq[t] = *reinterpret_cast<const bf16x8*>(qb + t * 512);

  const bf16* kb = Kp + (size_t)bh * BH_STRIDE + lh * 256 + l31 * 8;

  float s[16];
#pragma unroll
  for (int r = 0; r < 16; ++r) s[r] = 0.f;

  for (int nc = 0; nc < 64; ++nc) {
    const bf16* kp = kb + (size_t)nc * 2048;
    bf16x8 bk0 = *reinterpret_cast<const bf16x8*>(kp);
    bf16x8 bk1 = *reinterpret_cast<const bf16x8*>(kp + 512);
    bf16x8 bk2 = *reinterpret_cast<const bf16x8*>(kp + 1024);
    bf16x8 bk3 = *reinterpret_cast<const bf16x8*>(kp + 1536);
    f32x16 acc = {};
    acc = __builtin_amdgcn_mfma_f32_32x32x16_bf16(aq[0], bk0, acc, 0, 0, 0);
    acc = __builtin_amdgcn_mfma_f32_32x32x16_bf16(aq[1], bk1, acc, 0, 0, 0);
    acc = __builtin_amdgcn_mfma_f32_32x32x16_bf16(aq[2], bk2, acc, 0, 0, 0);
    acc = __builtin_amdgcn_mfma_f32_32x32x16_bf16(aq[3], bk3, acc, 0, 0, 0);
#pragma unroll
    for (int r = 0; r < 16; ++r) s[r] += __builtin_amdgcn_exp2f(acc[r]);
  }

  const int rowbase = bh * TT + q0 + 4 * lh;
#pragma unroll
  for (int r = 0; r < 16; ++r) {
    float sr = s[r];
    sr += __shfl_xor(sr, 1);
    sr += __shfl_xor(sr, 2);
    sr += __shfl_xor(sr, 4);
    sr += __shfl_xor(sr, 8);
    sr += __shfl_xor(sr, 16);
    const float v = -__builtin_amdgcn_logf(sr);   // -log2(sum)
    if (l31 == r) sums[rowbase + (r & 3) + 8 * (r >> 2)] = v;
  }
}

// ---- pass 2 kernel: recompute QK^T, LDS-staged 1KB-run stores ----
// Block = 64 q-rows x 2048 cols. Waves 0,1 share rows [0,32) (nc split),
// waves 2,3 share rows [32,64). 8 rounds x 256 cols: compute -> LDS -> sync ->
// cooperative nt store, one full 256-col row segment (1KB contiguous) per
// store instruction. grid 2048: bh = bid & 63 (XCD-local K), rowgroup = bid>>6.
__global__ __launch_bounds__(256, 2) void attn_wr_k(
    const bf16* __restrict__ Qp, const bf16* __restrict__ Kp,
    const float* __restrict__ sums, float* __restrict__ attn)
{
  __shared__ float lds[64][256];      // 64KB
  const int tid  = threadIdx.x;
  const int lane = tid & 63;
  const int wave = tid >> 6;          // 0..3
  const int l31  = lane & 31;
  const int lh   = lane >> 5;
  const int bh   = blockIdx.x & 63;
  const int rg   = blockIdx.x >> 6;   // 0..31
  const int stripe = wave >> 1;       // 0,1: which 32-row half
  const int nch    = wave & 1;        // 0,1: which nc half of each round
  const int tc   = rg * 2 + stripe;   // token chunk 0..63
  const int q0   = tc * 32;

  const bf16* qb = Qp + (size_t)bh * BH_STRIDE + (size_t)tc * 2048 + lh * 256 + l31 * 8;
  bf16x8 aq[4];
#pragma unroll
  for (int t = 0; t < 4; ++t)
    aq[t] = *reinterpret_cast<const bf16x8*>(qb + t * 512);

  const bf16* kb = Kp + (size_t)bh * BH_STRIDE + lh * 256 + l31 * 8;

  float sA[16];
  const int rowbase = bh * TT + q0 + 4 * lh;
#pragma unroll
  for (int r = 0; r < 16; ++r)
    sA[r] = sums[rowbase + (r & 3) + 8 * (r >> 2)];

  const int lrow0 = stripe * 32 + 4 * lh;              // LDS row base for this wave
  const int q0g   = rg * 64;                           // block's first global q-row
  const size_t gq = (size_t)bh * TT + q0g;             // global row base

  for (int round = 0; round < 8; ++round) {
    // ---- compute 4 nc tiles into LDS ----
#pragma unroll
    for (int i = 0; i < 4; ++i) {
      const int ncl = nch * 4 + i;                     // 0..7 within round
      const int nc  = round * 8 + ncl;
      const bf16* kp = kb + (size_t)nc * 2048;
      bf16x8 bk0 = *reinterpret_cast<const bf16x8*>(kp);
      bf16x8 bk1 = *reinterpret_cast<const bf16x8*>(kp + 512);
      bf16x8 bk2 = *reinterpret_cast<const bf16x8*>(kp + 1024);
      bf16x8 bk3 = *reinterpret_cast<const bf16x8*>(kp + 1536);
      f32x16 acc = {};
      acc = __builtin_amdgcn_mfma_f32_32x32x16_bf16(aq[0], bk0, acc, 0, 0, 0);
      acc = __builtin_amdgcn_mfma_f32_32x32x16_bf16(aq[1], bk1, acc, 0, 0, 0);
      acc = __builtin_amdgcn_mfma_f32_32x32x16_bf16(aq[2], bk2, acc, 0, 0, 0);
      acc = __builtin_amdgcn_mfma_f32_32x32x16_bf16(aq[3], bk3, acc, 0, 0, 0);
#pragma unroll
      for (int r = 0; r < 16; ++r) {
        const float p = __builtin_amdgcn_exp2f(acc[r] + sA[r]);
        lds[lrow0 + (r & 3) + 8 * (r >> 2)][ncl * 32 + l31] = p;
      }
    }
    __syncthreads();

    // ---- cooperative store: wave w -> rows [w*16, w*16+16), 1KB/instr ----
    const int cbase = round * 256;
#pragma unroll
    for (int rr = 0; rr < 16; ++rr) {
      const int row = wave * 16 + rr;
      const f32x4 v = *reinterpret_cast<const f32x4*>(&lds[row][lane * 4]);
      __builtin_nontemporal_store(
          v, reinterpret_cast<f32x4*>(attn + (gq + row) * TT + cbase + lane * 4));
    }
    __syncthreads();
  }
}

extern "C" void kernel_launch(void* const* d_in, const int* in_sizes, int n_in,
                              void* d_out, int out_size, void* d_ws, size_t ws_size,
                              hipStream_t stream) {
  // inputs: v,k,q, wq_w,wq_b, wk_w,wk_b, wv_w,wv_b, dense_w,dense_b, fc_w,fc_b
  const float* k_in = (const float*)d_in[1];
  const float* q_in = (const float*)d_in[2];
  const float* wq_w = (const float*)d_in[3];
  const float* wq_b = (const float*)d_in[4];
  const float* wk_w = (const float*)d_in[5];
  const float* wk_b = (const float*)d_in[6];
  float* out = (float*)d_out;

  // ws layout (bf16): qbf,kbf [8192x1024], w2 [2048x1024], Qp,Kp permuted, sums f32[64*2048]
  bf16* qbf  = (bf16*)d_ws;
  bf16* kbf  = qbf  + (size_t)NTOK * DM;
  bf16* w2   = kbf  + (size_t)NTOK * DM;     // wq rows then wk rows
  bf16* Qp   = w2   + (size_t)2 * DM * DM;
  bf16* Kp   = Qp   + (size_t)NTOK * DM;
  float* sums = (float*)(Kp + (size_t)NTOK * DM);

  const int prep_blocks = (2 * N4_QK + 2 * N4_W + N4_ONES) / 256;  // 18440
  prep_k<<<prep_blocks, 256, 0, stream>>>(q_in, k_in, wq_w, wk_w, qbf, out);

  gemm_qk<<<1024, 256, 0, stream>>>(qbf, kbf, w2, wq_b, wk_b, Qp, Kp);

  attn_sum_k<<<1024, 256, 0, stream>>>(Qp, Kp, sums);
  attn_wr_k<<<2048, 256, 0, stream>>>(Qp, Kp, sums, out + 8192);
}

// Round 12
// 286.606 us; speedup vs baseline: 1.4909x; 1.1350x over previous
//
#include <hip/hip_runtime.h>
#include <hip/hip_bf16.h>

#define NTOK 8192   // B*T
#define DM   1024
#define TT   2048
#define NH   16
#define BH_STRIDE (TT * 64)   // 131072 elems per (b,h) in permuted Q/K

typedef __hip_bfloat16 bf16;
typedef short bf16x8 __attribute__((ext_vector_type(8)));
typedef float f32x4  __attribute__((ext_vector_type(4)));
typedef float f32x16 __attribute__((ext_vector_type(16)));

#define N4_QK 2097152   // 8192*1024/4
#define N4_W  262144    // 1024*1024/4
#define N4_ONES 2048    // 8192/4

__device__ __forceinline__ void gload_lds16(const void* g, void* l) {
  __builtin_amdgcn_global_load_lds(
      (const __attribute__((address_space(1))) unsigned int*)g,
      (__attribute__((address_space(3))) unsigned int*)l, 16, 0, 0);
}

// ---- fused fp32->bf16 cvt (q,k,wq,wk -> contiguous bf16 ws) + ones for out0 ----
__global__ void prep_k(const float* __restrict__ q, const float* __restrict__ k,
                       const float* __restrict__ wq, const float* __restrict__ wk,
                       bf16* __restrict__ dst, float* __restrict__ ones) {
  const int i = blockIdx.x * 256 + threadIdx.x;
  const int total_cvt = 2 * N4_QK + 2 * N4_W;
  if (i < total_cvt) {
    const float* src;
    if (i < N4_QK)            src = q  + (size_t)i * 4;
    else if (i < 2 * N4_QK)   src = k  + (size_t)(i - N4_QK) * 4;
    else if (i < 2 * N4_QK + N4_W) src = wq + (size_t)(i - 2 * N4_QK) * 4;
    else                      src = wk + (size_t)(i - 2 * N4_QK - N4_W) * 4;
    float4 v = *reinterpret_cast<const float4*>(src);
    bf16 o[4] = {__float2bfloat16(v.x), __float2bfloat16(v.y),
                 __float2bfloat16(v.z), __float2bfloat16(v.w)};
    reinterpret_cast<ushort4*>(dst)[i] = *reinterpret_cast<ushort4*>(o);
  } else {
    const int j = i - total_cvt;          // 0..2047
    reinterpret_cast<float4*>(ones)[j] = make_float4(1.f, 1.f, 1.f, 1.f);
  }
}

// ---- merged projection GEMM, LDS-staged permuted epilogue, XCD-swizzled ----
// Qp/Kp[(b*16+h)][tc(64)][t(4)][lh(2)][tk(32)][e(8)]: element (tok,d) at
// tc=tok>>5, tk=tok&31, t=d>>4, lh=(d>>3)&1, e=d&7.
__global__ void gemm_qk(const bf16* __restrict__ Aq, const bf16* __restrict__ Ak,
                        const bf16* __restrict__ W,
                        const float* __restrict__ bq, const float* __restrict__ bk,
                        bf16* __restrict__ Qp, bf16* __restrict__ Kp)
{
  __shared__ bf16 sm[16384];          // 32KB: sA | sB during K-loop, permuted tile in epilogue
  bf16* sA = sm;
  bf16* sB = sm + 8192;
  const int tid  = threadIdx.x;
  const int lane = tid & 63;
  const int wave = tid >> 6;
  // XCD-aware swizzle: each XCD owns 8 consecutive bm values x all 16 bn
  const int swz  = ((blockIdx.x & 7) << 7) | (blockIdx.x >> 3);
  const int bm   = (swz >> 4) << 7;
  const int bn   = (swz & 15) << 7;
  const bool isQ = bn < 1024;
  const bf16* __restrict__ A = isQ ? Aq : Ak;
  const float scale = isQ ? 0.18033688011112042f : 1.0f;  // log2(e)/8
  const float* __restrict__ bias = isQ ? bq : (bk - 1024);
  bf16* __restrict__ dst = isQ ? Qp : Kp;

  const int wr   = (wave >> 1) << 6;
  const int wc   = (wave & 1) << 6;
  const int lrow = lane & 15;
  const int lk8  = (lane >> 4) << 3;
  const int trow = tid >> 3;
  const int tcol = (tid & 7) << 3;

  f32x4 acc[4][4] = {};

  for (int k0 = 0; k0 < 1024; k0 += 64) {
#pragma unroll
    for (int i = 0; i < 4; ++i) {
      const int r = trow + i * 32;
      gload_lds16(A + (size_t)(bm + r) * 1024 + k0 + tcol, sA + r * 64 + tcol);
      gload_lds16(W + (size_t)(bn + r) * 1024 + k0 + tcol, sB + r * 64 + tcol);
    }
    __syncthreads();

    bf16x8 af[4][2], bfr[4][2];
#pragma unroll
    for (int mi = 0; mi < 4; ++mi) {
      af[mi][0]  = *reinterpret_cast<const bf16x8*>(sA + (wr + mi * 16 + lrow) * 64 + lk8);
      af[mi][1]  = *reinterpret_cast<const bf16x8*>(sA + (wr + mi * 16 + lrow) * 64 + 32 + lk8);
      bfr[mi][0] = *reinterpret_cast<const bf16x8*>(sB + (wc + mi * 16 + lrow) * 64 + lk8);
      bfr[mi][1] = *reinterpret_cast<const bf16x8*>(sB + (wc + mi * 16 + lrow) * 64 + 32 + lk8);
    }
#pragma unroll
    for (int mi = 0; mi < 4; ++mi)
#pragma unroll
      for (int ni = 0; ni < 4; ++ni) {
        acc[mi][ni] = __builtin_amdgcn_mfma_f32_16x16x32_bf16(af[mi][0], bfr[ni][0], acc[mi][ni], 0, 0, 0);
        acc[mi][ni] = __builtin_amdgcn_mfma_f32_16x16x32_bf16(af[mi][1], bfr[ni][1], acc[mi][ni], 0, 0, 0);
      }
    __syncthreads();
  }

  // ---- epilogue: bias+scale+cvt into LDS in permuted order ----
#pragma unroll
  for (int mi = 0; mi < 4; ++mi)
#pragma unroll
    for (int ni = 0; ni < 4; ++ni) {
      const int col = bn + wc + ni * 16 + lrow;          // global feature 0..2047
      const float bv = bias[col];
      const int d  = col & 63;
      const int hp = (col >> 6) & 1;                     // which of the tile's 2 heads
      const int doff = ((d >> 4) * 2 + ((d >> 3) & 1)) * 256 + (d & 7);
#pragma unroll
      for (int j = 0; j < 4; ++j) {
        const int tokL = wr + mi * 16 + ((lane >> 4) << 2) + j;   // 0..127
        sm[hp * 8192 + ((tokL >> 5) << 11) + doff + ((tokL & 31) << 3)] =
            __float2bfloat16((acc[mi][ni][j] + bv) * scale);
      }
    }
  __syncthreads();

  // ---- coalesced stream-out: 2 heads x 16KB contiguous ----
  const int bb  = bm >> 11;
  const int hh0 = (bn >> 6) & 15;
  const size_t tc0 = (size_t)((bm & 2047) >> 5);
  const size_t g0 = (size_t)(bb * NH + hh0)     * BH_STRIDE + tc0 * 2048;
  const size_t g1 = (size_t)(bb * NH + hh0 + 1) * BH_STRIDE + tc0 * 2048;
#pragma unroll
  for (int rr = 0; rr < 4; ++rr) {
    const int off = rr * 2048 + tid * 8;
    *reinterpret_cast<ulonglong2*>(dst + g0 + off) =
        *reinterpret_cast<const ulonglong2*>(sm + off);
    *reinterpret_cast<ulonglong2*>(dst + g1 + off) =
        *reinterpret_cast<const ulonglong2*>(sm + 8192 + off);
  }
}

// ---- fused attn: per-block pass1 (row sums) + pass2 (LDS-staged 1KB writes) ----
// Block = 64 q-rows x 2048 cols, 4 waves. Waves (stripe=w>>1) own 32-row halves;
// nch=w&1 splits the nc range. Pass 1: each wave sums its 32-nc half, lane-merge
// via shfl_xor, cross-wave merge via psum LDS. Pass 2: 8 rounds compute->LDS->
// cooperative 1KB-run nt stores. grid 2048: bh = bid & 63 (XCD-local K).
__global__ __launch_bounds__(256, 2) void attn_fused_k(
    const bf16* __restrict__ Qp, const bf16* __restrict__ Kp, float* __restrict__ attn)
{
  __shared__ float lds[64][256];      // 64KB staging
  __shared__ float psum[4][32];       // per-wave partial row sums
  const int tid  = threadIdx.x;
  const int lane = tid & 63;
  const int wave = tid >> 6;          // 0..3
  const int l31  = lane & 31;
  const int lh   = lane >> 5;
  const int bh   = blockIdx.x & 63;
  const int rg   = blockIdx.x >> 6;   // 0..31
  const int stripe = wave >> 1;       // which 32-row half
  const int nch    = wave & 1;        // which nc half
  const int tc   = rg * 2 + stripe;   // token chunk 0..63

  const bf16* qb = Qp + (size_t)bh * BH_STRIDE + (size_t)tc * 2048 + lh * 256 + l31 * 8;
  bf16x8 aq[4];
#pragma unroll
  for (int t = 0; t < 4; ++t)
    aq[t] = *reinterpret_cast<const bf16x8*>(qb + t * 512);

  const bf16* kb = Kp + (size_t)bh * BH_STRIDE + lh * 256 + l31 * 8;

  // ---- pass 1: partial row sums over this wave's 32-nc half ----
  float s[16];
#pragma unroll
  for (int r = 0; r < 16; ++r) s[r] = 0.f;

  for (int i = 0; i < 32; ++i) {
    const int nc = nch * 32 + i;
    const bf16* kp = kb + (size_t)nc * 2048;
    bf16x8 bk0 = *reinterpret_cast<const bf16x8*>(kp);
    bf16x8 bk1 = *reinterpret_cast<const bf16x8*>(kp + 512);
    bf16x8 bk2 = *reinterpret_cast<const bf16x8*>(kp + 1024);
    bf16x8 bk3 = *reinterpret_cast<const bf16x8*>(kp + 1536);
    f32x16 acc = {};
    acc = __builtin_amdgcn_mfma_f32_32x32x16_bf16(aq[0], bk0, acc, 0, 0, 0);
    acc = __builtin_amdgcn_mfma_f32_32x32x16_bf16(aq[1], bk1, acc, 0, 0, 0);
    acc = __builtin_amdgcn_mfma_f32_32x32x16_bf16(aq[2], bk2, acc, 0, 0, 0);
    acc = __builtin_amdgcn_mfma_f32_32x32x16_bf16(aq[3], bk3, acc, 0, 0, 0);
#pragma unroll
    for (int r = 0; r < 16; ++r) s[r] += __builtin_amdgcn_exp2f(acc[r]);
  }

#pragma unroll
  for (int r = 0; r < 16; ++r) {
    float sr = s[r];
    sr += __shfl_xor(sr, 1);
    sr += __shfl_xor(sr, 2);
    sr += __shfl_xor(sr, 4);
    sr += __shfl_xor(sr, 8);
    sr += __shfl_xor(sr, 16);
    // lanes 0-31 (lh=0) hold rows +0, lanes 32-63 (lh=1) rows +4
    if (l31 == r) psum[wave][(r & 3) + 8 * (r >> 2) + 4 * lh] = sr;
  }
  __syncthreads();

  // ---- cross-wave merge: sA[r] = -log2(sum of both nc halves) ----
  float sA[16];
#pragma unroll
  for (int r = 0; r < 16; ++r) {
    const int row32 = (r & 3) + 8 * (r >> 2) + 4 * lh;
    sA[r] = -__builtin_amdgcn_logf(psum[stripe * 2][row32] + psum[stripe * 2 + 1][row32]);
  }
  __syncthreads();

  const int lrow0 = stripe * 32 + 4 * lh;
  const size_t gq = (size_t)bh * TT + rg * 64;         // block's global row base

  // ---- pass 2: 8 rounds, compute -> LDS -> cooperative 1KB-run stores ----
  for (int round = 0; round < 8; ++round) {
#pragma unroll
    for (int i = 0; i < 4; ++i) {
      const int ncl = nch * 4 + i;                     // 0..7 within round
      const int nc  = round * 8 + ncl;
      const bf16* kp = kb + (size_t)nc * 2048;
      bf16x8 bk0 = *reinterpret_cast<const bf16x8*>(kp);
      bf16x8 bk1 = *reinterpret_cast<const bf16x8*>(kp + 512);
      bf16x8 bk2 = *reinterpret_cast<const bf16x8*>(kp + 1024);
      bf16x8 bk3 = *reinterpret_cast<const bf16x8*>(kp + 1536);
      f32x16 acc = {};
      acc = __builtin_amdgcn_mfma_f32_32x32x16_bf16(aq[0], bk0, acc, 0, 0, 0);
      acc = __builtin_amdgcn_mfma_f32_32x32x16_bf16(aq[1], bk1, acc, 0, 0, 0);
      acc = __builtin_amdgcn_mfma_f32_32x32x16_bf16(aq[2], bk2, acc, 0, 0, 0);
      acc = __builtin_amdgcn_mfma_f32_32x32x16_bf16(aq[3], bk3, acc, 0, 0, 0);
#pragma unroll
      for (int r = 0; r < 16; ++r) {
        const float p = __builtin_amdgcn_exp2f(acc[r] + sA[r]);
        lds[lrow0 + (r & 3) + 8 * (r >> 2)][ncl * 32 + l31] = p;
      }
    }
    __syncthreads();

    const int cbase = round * 256;
#pragma unroll
    for (int rr = 0; rr < 16; ++rr) {
      const int row = wave * 16 + rr;
      const f32x4 v = *reinterpret_cast<const f32x4*>(&lds[row][lane * 4]);
      __builtin_nontemporal_store(
          v, reinterpret_cast<f32x4*>(attn + (gq + row) * TT + cbase + lane * 4));
    }
    __syncthreads();
  }
}

extern "C" void kernel_launch(void* const* d_in, const int* in_sizes, int n_in,
                              void* d_out, int out_size, void* d_ws, size_t ws_size,
                              hipStream_t stream) {
  // inputs: v,k,q, wq_w,wq_b, wk_w,wk_b, wv_w,wv_b, dense_w,dense_b, fc_w,fc_b
  const float* k_in = (const float*)d_in[1];
  const float* q_in = (const float*)d_in[2];
  const float* wq_w = (const float*)d_in[3];
  const float* wq_b = (const float*)d_in[4];
  const float* wk_w = (const float*)d_in[5];
  const float* wk_b = (const float*)d_in[6];
  float* out = (float*)d_out;

  // ws layout (bf16): qbf,kbf [8192x1024], w2 [2048x1024], Qp,Kp permuted
  bf16* qbf  = (bf16*)d_ws;
  bf16* kbf  = qbf  + (size_t)NTOK * DM;
  bf16* w2   = kbf  + (size_t)NTOK * DM;     // wq rows then wk rows
  bf16* Qp   = w2   + (size_t)2 * DM * DM;
  bf16* Kp   = Qp   + (size_t)NTOK * DM;

  const int prep_blocks = (2 * N4_QK + 2 * N4_W + N4_ONES) / 256;  // 18440
  prep_k<<<prep_blocks, 256, 0, stream>>>(q_in, k_in, wq_w, wk_w, qbf, out);

  gemm_qk<<<1024, 256, 0, stream>>>(qbf, kbf, w2, wq_b, wk_b, Qp, Kp);

  attn_fused_k<<<2048, 256, 0, stream>>>(Qp, Kp, out + 8192);
}